// Round 6
// baseline (193.121 us; speedup 1.0000x reference)
//
#include <hip/hip_runtime.h>

#define NGRAPH 1000
#define P      100
#define EPG    1200
#define INF    16
#define HID    64
#define NOUT   5

// r24: dual bf16-plane activations + in-kernel adjacency build.
//  - Post-mortem r19-r23: VGPR pinned at 64 => compiler rematerialized the
//    "hoisted" adjacency frags from GLOBAL (FETCH 19->38MB), and abuild's
//    25.6MB dirty aint lines thrashed L2 (WRITE 40MB). bsplit repack ~950
//    VALU/chunk was r19's 55% VALUBusy.
//  - Activations stored as TWO bf16 planes Ahi/Alo [node][feat], FSTR=96:
//      * W-phase A-frag = direct ds_read_b128 per plane (ZERO repack VALU).
//      * prop B-frag = 8 ds_read_u16/plane, offset-immediate folded.
//      * writes: RNE hi/lo split (r20-verified numerics).
//  - Swizzle col ^= ((row>>3)&3)<<3: prop xor == q<<3 (lane-uniform) =>
//    quad collision 4-way -> 2-way (free); W b128 ~4-way (accepted).
//  - Adjacency counts built in LDS (cnt aliases the plane region, consumed
//    into registers BEFORE the feat load overwrites it; barrier-fenced so
//    the compiler cannot remat from LDS). abuild kernel + 25.6MB ws DELETED.
//  - LDS: planes 38,400 + meta 512 = 38.9KB -> 4 blocks/CU.
// HARD RULES: no runtime-indexed local arrays; verified MFMA lane mappings
// (A: row=l&15,k=8q+j; B: col=l&15,k=8q+j; D: col=l&15,row=4q+r) unchanged.

#define FSTR   96
#define T1OFF  64
#define T2OFF  80

#define RK1 64
#define RK2 208
#define L1HI 0
#define L1LO 4096
#define L2HI 8192
#define L2LO 21504
#define L3HI 34816
#define L3LO 48128

typedef short short8 __attribute__((ext_vector_type(8)));
typedef float f32x4  __attribute__((ext_vector_type(4)));

// swizzled short-index into a plane: flips feat bits 3..4 by node bits 3..4
__device__ __forceinline__ int swf(int row, int col) {
    return row * FSTR + (col ^ (((row >> 3) & 3) << 3));
}

// RNE split of fp32 into (bf16hi<<16)|bf16lo
__device__ __forceinline__ unsigned packsplit(float x) {
    unsigned u  = __float_as_uint(x);
    unsigned hi = (u + 0x7fffu + ((u >> 16) & 1u)) >> 16;
    float r = x - __uint_as_float(hi << 16);
    unsigned v  = __float_as_uint(r);
    unsigned lo = (v + 0x7fffu + ((v >> 16) & 1u)) >> 16;
    return (hi << 16) | (lo & 0xffffu);
}

__device__ __forceinline__ float up2(short h, short l) {
    return __uint_as_float(((unsigned)(unsigned short)h) << 16) +
           __uint_as_float(((unsigned)(unsigned short)l) << 16);
}

// ---- W split/transpose pre-kernel (unchanged tables) ----
__global__ __launch_bounds__(256) void wprep(
    const float* __restrict__ W1, const float* __restrict__ W2,
    const float* __restrict__ W3, short* __restrict__ wt)
{
    const int i0 = blockIdx.x * blockDim.x + threadIdx.x;
    const int stride = gridDim.x * blockDim.x;
    for (int e = i0; e < HID * RK1; e += stride) {
        int c = e / RK1, r = e % RK1;
        float v = (r < 3 * INF) ? W1[r * HID + c] : 0.f;
        unsigned p = packsplit(v);
        wt[L1HI + e] = (short)(p >> 16);
        wt[L1LO + e] = (short)(p & 0xffffu);
    }
    for (int e = i0; e < HID * RK2; e += stride) {
        int c = e / RK2, r = e % RK2;
        float v2 = (r < 3 * HID) ? W2[r * HID + c] : 0.f;
        float v3 = (r < 3 * HID) ? W3[r * HID + c] : 0.f;
        unsigned p2 = packsplit(v2), p3 = packsplit(v3);
        wt[L2HI + e] = (short)(p2 >> 16); wt[L2LO + e] = (short)(p2 & 0xffffu);
        wt[L3HI + e] = (short)(p3 >> 16); wt[L3LO + e] = (short)(p3 & 0xffffu);
    }
}

// ---- one dense propagation reading the bf16 planes ----
// SECOND=0: T1 = -d^2 (Aint @ src);  SECOND=1: T2 = -2 d^2 (Aint @ src) - Y
template <int SECOND>
__device__ __forceinline__ void dense_prop(
    short* __restrict__ Ahi, short* __restrict__ Alo,
    short8 a00, short8 a01, short8 a02, short8 a03,
    short8 a10, short8 a11, short8 a12, short8 a13,
    bool has2, int srcoff, int dstoff, int ycb,
    int rb0, int rb1, f32x4 dv0, f32x4 dv1, int lane)
{
    const int n16 = lane & 15;
    const int q   = lane >> 4;
    const int kq  = q * 8;
    // prop rows m = 32*KK + 8q + j  =>  ((m>>3)&3) == q  => swizzled col is
    // lane-uniform for ALL prop reads:
    const int c = (srcoff + n16) ^ (q << 3);
    f32x4 p0, p1;
    p0[0]=0.f; p0[1]=0.f; p0[2]=0.f; p0[3]=0.f;
    p1[0]=0.f; p1[1]=0.f; p1[2]=0.f; p1[3]=0.f;

#define PROPK(KK, A0, A1) { \
    const int b0 = (KK * 32 + kq) * FSTR + c; \
    short8 bhi, blo; \
    if (KK < 3) { \
        bhi[0]=Ahi[b0        ]; blo[0]=Alo[b0        ]; \
        bhi[1]=Ahi[b0+1*FSTR ]; blo[1]=Alo[b0+1*FSTR ]; \
        bhi[2]=Ahi[b0+2*FSTR ]; blo[2]=Alo[b0+2*FSTR ]; \
        bhi[3]=Ahi[b0+3*FSTR ]; blo[3]=Alo[b0+3*FSTR ]; \
        bhi[4]=Ahi[b0+4*FSTR ]; blo[4]=Alo[b0+4*FSTR ]; \
        bhi[5]=Ahi[b0+5*FSTR ]; blo[5]=Alo[b0+5*FSTR ]; \
        bhi[6]=Ahi[b0+6*FSTR ]; blo[6]=Alo[b0+6*FSTR ]; \
        bhi[7]=Ahi[b0+7*FSTR ]; blo[7]=Alo[b0+7*FSTR ]; \
    } else { \
        const int m0 = 96 + kq; \
        const int i0 = (m0+0 < P ? (m0+0)*FSTR : 0) + c; \
        const int i1 = (m0+1 < P ? (m0+1)*FSTR : 0) + c; \
        const int i2 = (m0+2 < P ? (m0+2)*FSTR : 0) + c; \
        const int i3 = (m0+3 < P ? (m0+3)*FSTR : 0) + c; \
        bhi[0]=Ahi[i0]; blo[0]=Alo[i0]; \
        bhi[1]=Ahi[i1]; blo[1]=Alo[i1]; \
        bhi[2]=Ahi[i2]; blo[2]=Alo[i2]; \
        bhi[3]=Ahi[i3]; blo[3]=Alo[i3]; \
        bhi[4]=0; blo[4]=0; \
        bhi[5]=0; blo[5]=0; \
        bhi[6]=0; blo[6]=0; \
        bhi[7]=0; blo[7]=0; \
    } \
    p0 = __builtin_amdgcn_mfma_f32_16x16x32_bf16(A0, bhi, p0, 0, 0, 0); \
    p0 = __builtin_amdgcn_mfma_f32_16x16x32_bf16(A0, blo, p0, 0, 0, 0); \
    if (has2) { \
        p1 = __builtin_amdgcn_mfma_f32_16x16x32_bf16(A1, bhi, p1, 0, 0, 0); \
        p1 = __builtin_amdgcn_mfma_f32_16x16x32_bf16(A1, blo, p1, 0, 0, 0); \
    } }

    PROPK(0, a00, a10)
    PROPK(1, a01, a11)
    PROPK(2, a02, a12)
    PROPK(3, a03, a13)
#undef PROPK

#pragma unroll
    for (int r = 0; r < 4; r++) {
        const int row = rb0 + q * 4 + r;
        const float d2 = dv0[r] * dv0[r];
        float o;
        if (SECOND) {
            const int yi = swf(row, ycb + n16);
            o = -2.f * d2 * p0[r] - up2(Ahi[yi], Alo[yi]);
        } else o = -d2 * p0[r];
        const int di = swf(row, dstoff + n16);
        const unsigned pp = packsplit(o);
        Ahi[di] = (short)(pp >> 16); Alo[di] = (short)pp;
    }
    if (has2) {
#pragma unroll
        for (int r = 0; r < 4; r++) {
            const int row = rb1 + q * 4 + r;
            if (rb1 != 84 || row >= 96) {            // tile-6 overlap guard
                const float d2 = dv1[r] * dv1[r];
                float o;
                if (SECOND) {
                    const int yi = swf(row, ycb + n16);
                    o = -2.f * d2 * p1[r] - up2(Ahi[yi], Alo[yi]);
                } else o = -d2 * p1[r];
                const int di = swf(row, dstoff + n16);
                const unsigned pp = packsplit(o);
                Ahi[di] = (short)(pp >> 16); Alo[di] = (short)pp;
            }
        }
    }
}

// ---- one ChebConv layer ----
template <int F, int FINAL>
__device__ __forceinline__ void cheb_layer(
    short* __restrict__ Ahi, short* __restrict__ Alo,
    const float* __restrict__ dinv,
    short8 a00, short8 a01, short8 a02, short8 a03,
    short8 a10, short8 a11, short8 a12, short8 a13, bool has2,
    const short* __restrict__ whi, const short* __restrict__ wlo,
    const float* __restrict__ bias,
    int tid, int rb0, int rb1, f32x4 dv0, f32x4 dv1)
{
    const int RK   = 3 * F + 16;
    const int lane = tid & 63;
    const int wv   = tid >> 6;
    const int n16  = lane & 15;
    const int q    = lane >> 4;
    const int ncol = (wv << 4) + n16;

    f32x4 acc[7];
#pragma unroll
    for (int t = 0; t < 7; t++) { acc[t][0]=0.f; acc[t][1]=0.f; acc[t][2]=0.f; acc[t][3]=0.f; }

    for (int cb = 0; cb < F; cb += 16) {
        dense_prop<0>(Ahi, Alo, a00,a01,a02,a03, a10,a11,a12,a13, has2,
                      cb,    T1OFF, 0,  rb0, rb1, dv0, dv1, lane);
        __syncthreads();
        dense_prop<1>(Ahi, Alo, a00,a01,a02,a03, a10,a11,a12,a13, has2,
                      T1OFF, T2OFF, cb, rb0, rb1, dv0, dv1, lane);
        __syncthreads();

        // W partial: chunk K-layout [Y16 | T1_16 | T2_16 | zero16], 2 K-steps
#pragma unroll
        for (int ks = 0; ks < 2; ks++) {
            int wr, aoff;
            if (ks == 0) {
                wr   = (q == 0) ? cb : (q == 1) ? cb + 8 : (q == 2) ? F + cb : F + cb + 8;
                aoff = (q == 0) ? cb : (q == 1) ? cb + 8 : (q == 2) ? T1OFF  : T1OFF + 8;
            } else {
                wr   = (q == 0) ? 2*F + cb : (q == 1) ? 2*F + cb + 8 : (q == 2) ? 3*F : 3*F + 8;
                aoff = (q == 0) ? T2OFF    : (q == 1) ? T2OFF + 8    : (q == 2) ? T1OFF : T1OFF + 8;
            }
            const short8 bhi = *(const short8*)&whi[ncol * RK + wr];
            const short8 blo = *(const short8*)&wlo[ncol * RK + wr];
#pragma unroll
            for (int t = 0; t < 7; t++) {
                const int row = ((t < 6) ? t * 16 : 84) + n16;
                const int ax  = row * FSTR + (aoff ^ (((row >> 3) & 3) << 3));
                const short8 ahi = *(const short8*)&Ahi[ax];   // 16B-aligned
                const short8 alo = *(const short8*)&Alo[ax];
                acc[t] = __builtin_amdgcn_mfma_f32_16x16x32_bf16(ahi, bhi, acc[t], 0, 0, 0);
                acc[t] = __builtin_amdgcn_mfma_f32_16x16x32_bf16(ahi, blo, acc[t], 0, 0, 0);
                acc[t] = __builtin_amdgcn_mfma_f32_16x16x32_bf16(alo, bhi, acc[t], 0, 0, 0);
            }
        }
        __syncthreads();
    }

    // Epilogue (D: col=lane&15, row=4*(lane>>4)+reg; tile 6 -> rows 84..99)
    const float bcol = bias[ncol];
#pragma unroll
    for (int t = 0; t < 7; t++) {
        const int rbase = ((t < 6) ? t * 16 : 84) + q * 4;
#pragma unroll
        for (int r = 0; r < 4; r++) {
            const int row = rbase + r;
            if (t < 6 || row >= 96) {
                const float dn = dinv[row];
                const float v = acc[t][r];
                float o;
                if (FINAL) o = fmaxf(v * (1.0f / dn) + bcol, 0.f);
                else       o = fmaxf(v + bcol * dn, 0.f);
                const int oi = swf(row, ncol);
                const unsigned pp = packsplit(o);
                Ahi[oi] = (short)(pp >> 16); Alo[oi] = (short)pp;
            }
        }
    }
    __syncthreads();
}

__global__ __launch_bounds__(256, 4) void gnn_kernel(
    const float* __restrict__ feat,
    const int* __restrict__ src, const int* __restrict__ dst,
    const float* __restrict__ b1, const float* __restrict__ b2,
    const float* __restrict__ b3,
    const float* __restrict__ Wfc, const float* __restrict__ bfc,
    const short* __restrict__ wt,
    float* __restrict__ out)
{
    // planes region (38,912 B) doubles as the adjacency-count buffer
    __shared__ __align__(16) unsigned ldsu[9728];
    __shared__ float meta[128];                    // dinv[100] + pool[20]
    short* Ahi = (short*)ldsu;                     // 9600 shorts
    short* Alo = (short*)ldsu + 9600;              // 9600 shorts
    unsigned* cnt = ldsu;                          // 6400 u32 (build phase)

    const int g = blockIdx.x;
    const int tid = threadIdx.x;
    const int base = g * P;
    const int* srcg = src + g * EPG;
    const int* dstg = dst + g * EPG;

    // ---- phase A: zero counts + degrees ----
    int* deg = (int*)meta;
    for (int i = tid; i < 6400; i += 256) cnt[i] = 0u;
    for (int i = tid; i < P; i += 256) deg[i] = 0;
    __syncthreads();
    // ---- phase B: single edge pass (degree + dense counts) ----
    for (int e = tid; e < EPG; e += 256) {
        int s = srcg[e] - base;
        int d = dstg[e] - base;
        atomicAdd(&deg[d], 1);
        atomicAdd(&cnt[d * 64 + (s >> 1)], 1u << ((s & 1) * 16));
    }
    __syncthreads();
    // ---- phase C: dinv + adjacency frag extraction (cnt -> registers) ----
    for (int i = tid; i < P; i += 256) {
        int dg = deg[i];
        meta[i] = rsqrtf((float)(dg > 1 ? dg : 1));
    }
    const int lane = tid & 63, wv = tid >> 6, q = lane >> 4, n16 = lane & 15;
    const int rb0 = wv * 16;
    const int t2i = wv + 4;
    const int rb1 = (t2i >= 6) ? 84 : t2i * 16;
    const bool has2 = (wv < 3);
    const int arow0 = rb0 + n16;
    const int arow1 = (has2 ? rb1 : rb0) + n16;
    short8 a00, a01, a02, a03, a10, a11, a12, a13;
#define MKA(VAR, AR, KK) { \
    const unsigned w0 = cnt[(AR) * 64 + (KK) * 16 + q * 4 + 0]; \
    const unsigned w1 = cnt[(AR) * 64 + (KK) * 16 + q * 4 + 1]; \
    const unsigned w2 = cnt[(AR) * 64 + (KK) * 16 + q * 4 + 2]; \
    const unsigned w3 = cnt[(AR) * 64 + (KK) * 16 + q * 4 + 3]; \
    short8 t; \
    t[0] = (short)(__float_as_uint((float)(w0 & 0xffffu)) >> 16); \
    t[1] = (short)(__float_as_uint((float)(w0 >> 16))     >> 16); \
    t[2] = (short)(__float_as_uint((float)(w1 & 0xffffu)) >> 16); \
    t[3] = (short)(__float_as_uint((float)(w1 >> 16))     >> 16); \
    t[4] = (short)(__float_as_uint((float)(w2 & 0xffffu)) >> 16); \
    t[5] = (short)(__float_as_uint((float)(w2 >> 16))     >> 16); \
    t[6] = (short)(__float_as_uint((float)(w3 & 0xffffu)) >> 16); \
    t[7] = (short)(__float_as_uint((float)(w3 >> 16))     >> 16); \
    VAR = t; }
    MKA(a00, arow0, 0)  MKA(a01, arow0, 1)  MKA(a02, arow0, 2)  MKA(a03, arow0, 3)
    MKA(a10, arow1, 0)  MKA(a11, arow1, 1)  MKA(a12, arow1, 2)  MKA(a13, arow1, 3)
#undef MKA
    __syncthreads();   // extraction complete before planes overwrite cnt

    // ---- phase D: dinv regs + feat load prescaled into planes ----
    f32x4 dv0, dv1;
#pragma unroll
    for (int r = 0; r < 4; r++) {
        dv0[r] = meta[rb0 + q * 4 + r];
        dv1[r] = meta[(has2 ? rb1 : rb0) + q * 4 + r];
    }
    for (int i = tid; i < P * INF / 4; i += 256) {
        int n = i >> 2, f0 = (i & 3) * 4;
        float4 v = *(const float4*)&feat[(size_t)base * INF + i * 4];
        float dn = meta[n];
        unsigned p0 = packsplit(v.x * dn), p1 = packsplit(v.y * dn);
        unsigned p2 = packsplit(v.z * dn), p3 = packsplit(v.w * dn);
        const int bi = swf(n, f0);                 // 4-aligned short index
        *(unsigned*)&Ahi[bi]     = (p0 >> 16) | (p1 & 0xffff0000u);
        *(unsigned*)&Ahi[bi + 2] = (p2 >> 16) | (p3 & 0xffff0000u);
        *(unsigned*)&Alo[bi]     = (p0 & 0xffffu) | (p1 << 16);
        *(unsigned*)&Alo[bi + 2] = (p2 & 0xffffu) | (p3 << 16);
    }
    __syncthreads();

    cheb_layer<INF, 0>(Ahi, Alo, meta, a00,a01,a02,a03, a10,a11,a12,a13, has2,
                       wt + L1HI, wt + L1LO, b1, tid, rb0, rb1, dv0, dv1);
    cheb_layer<HID, 0>(Ahi, Alo, meta, a00,a01,a02,a03, a10,a11,a12,a13, has2,
                       wt + L2HI, wt + L2LO, b2, tid, rb0, rb1, dv0, dv1);
    cheb_layer<HID, 1>(Ahi, Alo, meta, a00,a01,a02,a03, a10,a11,a12,a13, has2,
                       wt + L3HI, wt + L3LO, b3, tid, rb0, rb1, dv0, dv1);

    // ---- mean pool + FC: per-wave column sums -> partial FC -> shuffle ----
    {
        const int l = tid & 63, w = tid >> 6;
        float s = 0.f;
        for (int n = w; n < P; n += 4) {
            const int ii = swf(n, l);
            s += up2(Ahi[ii], Alo[ii]);
        }
        float o0 = s * Wfc[l * NOUT + 0];
        float o1 = s * Wfc[l * NOUT + 1];
        float o2 = s * Wfc[l * NOUT + 2];
        float o3 = s * Wfc[l * NOUT + 3];
        float o4 = s * Wfc[l * NOUT + 4];
#pragma unroll
        for (int d = 1; d < 64; d <<= 1) {
            o0 += __shfl_xor(o0, d);
            o1 += __shfl_xor(o1, d);
            o2 += __shfl_xor(o2, d);
            o3 += __shfl_xor(o3, d);
            o4 += __shfl_xor(o4, d);
        }
        if (l == 0) {
            meta[100 + w * NOUT + 0] = o0;
            meta[100 + w * NOUT + 1] = o1;
            meta[100 + w * NOUT + 2] = o2;
            meta[100 + w * NOUT + 3] = o3;
            meta[100 + w * NOUT + 4] = o4;
        }
    }
    __syncthreads();
    if (tid < NOUT) {
        float o = meta[100 + tid] + meta[105 + tid] + meta[110 + tid] + meta[115 + tid];
        out[g * NOUT + tid] = bfc[tid] + o * (1.0f / P);
    }
}

extern "C" void kernel_launch(void* const* d_in, const int* in_sizes, int n_in,
                              void* d_out, int out_size, void* d_ws, size_t ws_size,
                              hipStream_t stream)
{
    const float* feat = (const float*)d_in[0];
    const int*   src  = (const int*)d_in[1];
    const int*   dst  = (const int*)d_in[2];
    const float* W1  = (const float*)d_in[5];
    const float* b1  = (const float*)d_in[6];
    const float* W2  = (const float*)d_in[7];
    const float* b2  = (const float*)d_in[8];
    const float* W3  = (const float*)d_in[9];
    const float* b3  = (const float*)d_in[10];
    const float* Wfc = (const float*)d_in[11];
    const float* bfc = (const float*)d_in[12];
    float* out = (float*)d_out;

    short* wt = (short*)d_ws;                   // 122,880 B only

    wprep<<<64, 256, 0, stream>>>(W1, W2, W3, wt);
    gnn_kernel<<<NGRAPH, 256, 0, stream>>>(feat, src, dst,
                                           b1, b2, b3, Wfc, bfc, wt, out);
}